// Round 4
// baseline (7163.013 us; speedup 1.0000x reference)
//
#include <hip/hip_runtime.h>
#include <hip/hip_bf16.h>
#include <cstdint>

// ---------------------------------------------------------------------------
// SentenceEncoder: per 8-step chunk: gather_chunk (emb -> Xc bf16, 4 MB,
// L2-resident) -> xproj_gemm (Xb = Xc @ Wih^T + bias) -> lstm_chunk
// (persistent, 256 blocks = 1/CU, 8 steps with per-m-group spin barriers,
// W_hh LDS-resident, c/hmax register-resident) -> final linear+sigmoid.
//
// Gate permutation (lane-aligned): p = nb*64 + g*16 + jl, original row
// r = g*1024 + nb*16 + jl. In MFMA C/D layout acc[mi][g][rg] holds all four
// gate pre-acts for one (row, j) in ONE lane -> cell update in registers.
//
// NO cooperative launch (R3 suspect); ws capped at ~57 MB (R3 overran the
// R2-proven 119.5 MB floor by 256 B).
// ---------------------------------------------------------------------------

typedef __bf16 bf16x8 __attribute__((ext_vector_type(8)));
typedef float f32x4 __attribute__((ext_vector_type(4)));

__device__ __forceinline__ float sigm(float x) {
    return 1.0f / (1.0f + __expf(-x));
}
__device__ __forceinline__ float tanh_fast(float x) {
    x = fminf(15.0f, fmaxf(-15.0f, x));
    float e = __expf(2.0f * x);
    return (e - 1.0f) / (e + 1.0f);
}
__device__ __forceinline__ ushort f2bu(float f) {
    __hip_bfloat16 h = __float2bfloat16(f);
    return __builtin_bit_cast(unsigned short, h);
}
__device__ __forceinline__ float bu2f(ushort u) {
    return __uint_as_float(((unsigned)u) << 16);
}
__device__ __forceinline__ void gl_lds16(const void* g, void* l) {
    __builtin_amdgcn_global_load_lds(
        (const __attribute__((address_space(1))) unsigned int*)g,
        (__attribute__((address_space(3))) unsigned int*)l, 16, 0, 0);
}

// ---------------------------------------------------------------------------
// Kernel 1: weight prep. WcT[p][k] bf16, p = nb*64 + g*16 + jl ->
// r = g*1024 + nb*16 + jl. k 0..511 = W_ih, 512..1535 = W_hh.
// ---------------------------------------------------------------------------
__global__ void prep_weights(const float* __restrict__ Wih,
                             const float* __restrict__ Whh,
                             const float* __restrict__ bih,
                             const float* __restrict__ bhh,
                             __hip_bfloat16* __restrict__ WcT,
                             float* __restrict__ biasc) {
    int p = blockIdx.y;
    int k = blockIdx.x * blockDim.x + threadIdx.x;  // 0..1535
    int nb = p >> 6;
    int g = (p >> 4) & 3;
    int jl = p & 15;
    int r = g * 1024 + nb * 16 + jl;
    float v = (k < 512) ? Wih[(size_t)r * 512 + k]
                        : Whh[(size_t)r * 1024 + (k - 512)];
    WcT[(size_t)p * 1536 + k] = __float2bfloat16(v);
    if (k == 0) biasc[p] = bih[r] + bhh[r];
}

// ---------------------------------------------------------------------------
// Kernel 2: per-chunk embedding gather. Xc[rr][512] bf16, rr = (t-t0)*512+b'.
// grid 4096, block 256.
// ---------------------------------------------------------------------------
__global__ void gather_chunk(const int* __restrict__ q,
                             const int* __restrict__ s,
                             const float* __restrict__ emb,
                             ushort* __restrict__ Xc, int t0) {
    int rr = blockIdx.x;  // 0..4095
    int t = t0 + (rr >> 9);
    int b = rr & 511;
    int tok = (b < 256) ? q[b * 128 + t] : s[(b - 256) * 128 + t];
    const float2* src = (const float2*)(emb + (size_t)tok * 512);
    float2 v = src[threadIdx.x];
    ushort2 o;
    o.x = f2bu(v.x);
    o.y = f2bu(v.y);
    ((ushort2*)(Xc + (size_t)rr * 512))[threadIdx.x] = o;
}

// ---------------------------------------------------------------------------
// Kernel 3: state init. c=0, hmax=-1e30, h0=0, barrier counters=0.
// ---------------------------------------------------------------------------
__global__ void init_state(float* __restrict__ C, float* __restrict__ HMAX,
                           ushort* __restrict__ H0, int* __restrict__ cnt) {
    int i = blockIdx.x * 256 + threadIdx.x;
    C[i] = 0.0f;
    HMAX[i] = -1e30f;
    H0[i] = 0;
    if (i < 64) cnt[i] = 0;
}

// ---------------------------------------------------------------------------
// Kernel 4: Xb[rr][p] = bias[p] + sum_k Xc[rr][k]*WcT[p][k], K=512.
// 128x128 tiles, BK=128, gl_lds16 + XOR swizzle. grid (32 nt, 32 mt).
// ---------------------------------------------------------------------------
__global__ __launch_bounds__(256, 2) void xproj_gemm(
    const ushort* __restrict__ Xc,     // [4096][512] bf16
    const ushort* __restrict__ WcT,    // [4096][1536] bf16
    const float* __restrict__ biasc,   // [4096]
    ushort* __restrict__ Xb) {         // [4096][4096] bf16
    __shared__ __align__(16) ushort As[128 * 128];
    __shared__ __align__(16) ushort Bs[128 * 128];

    const int tid = threadIdx.x;
    const int n0 = blockIdx.x * 128;
    const int m0 = blockIdx.y * 128;
    const int lane = tid & 63;
    const int w = tid >> 6;
    const int quad = lane >> 4;
    const int l16 = lane & 15;
    const int wm = (w >> 1) * 64;
    const int wn = (w & 1) * 64;

    f32x4 acc[4][4] = {};

    for (int it = 0; it < 4; ++it) {
        const int k0 = it * 128;
        __syncthreads();
#pragma unroll
        for (int i = 0; i < 8; ++i) {
            int u = i * 256 + tid;
            int r = u >> 4;
            int cs = (u & 15) ^ (r & 15);
            gl_lds16(Xc + (size_t)(m0 + r) * 512 + k0 + cs * 8,
                     (ushort*)As + (size_t)u * 8);
            gl_lds16(WcT + (size_t)(n0 + r) * 1536 + k0 + cs * 8,
                     (ushort*)Bs + (size_t)u * 8);
        }
        __syncthreads();
#pragma unroll
        for (int kb = 0; kb < 4; ++kb) {
            bf16x8 af[4], bfr[4];
            const int vsel = (kb << 2) | quad;
#pragma unroll
            for (int mi = 0; mi < 4; ++mi)
                af[mi] = *(const bf16x8*)(As +
                    (((wm + mi * 16 + l16) << 4) + (vsel ^ l16)) * 8);
#pragma unroll
            for (int ni = 0; ni < 4; ++ni)
                bfr[ni] = *(const bf16x8*)(Bs +
                    (((wn + ni * 16 + l16) << 4) + (vsel ^ l16)) * 8);
#pragma unroll
            for (int mi = 0; mi < 4; ++mi)
#pragma unroll
                for (int ni = 0; ni < 4; ++ni)
                    acc[mi][ni] = __builtin_amdgcn_mfma_f32_16x16x32_bf16(
                        af[mi], bfr[ni], acc[mi][ni], 0, 0, 0);
        }
    }

#pragma unroll
    for (int mi = 0; mi < 4; ++mi)
#pragma unroll
        for (int ni = 0; ni < 4; ++ni) {
            float bv = biasc[n0 + wn + ni * 16 + l16];
#pragma unroll
            for (int rg = 0; rg < 4; ++rg)
                Xb[(size_t)(m0 + wm + mi * 16 + quad * 4 + rg) * 4096 +
                   (n0 + wn + ni * 16 + l16)] = f2bu(acc[mi][ni][rg] + bv);
        }
}

// ---------------------------------------------------------------------------
// Kernel 5: persistent LSTM chunk — 8 steps, per-m-group spin barriers.
// Plain launch, grid 256 = 1 block/CU (129 KB LDS) -> all blocks resident.
// Block = (mg: 128 batch rows) x (nb: 64 gate cols). mg = (b&7)>>1 pins each
// m-group to an XCD pair (h traffic + barrier stay in 2 L2s).
// ---------------------------------------------------------------------------
__global__ __launch_bounds__(256, 1) void lstm_chunk(
    const ushort* __restrict__ Xb,    // [4096][4096] bf16 (bias included)
    const ushort* __restrict__ WcT,   // [4096][1536] bf16
    ushort* __restrict__ Hbuf,        // [2][512][1024] bf16
    float* __restrict__ C,            // [512][1024]
    float* __restrict__ HMAX,         // [512][1024]
    int* __restrict__ bcnt,           // 4 monotonic counters
    int t0, int tgt0) {
    __shared__ ushort Ws[64][1032];  // 129 KB; stride 1032 -> 2-way (free)

    const int tid = threadIdx.x;
    const int b = blockIdx.x;
    const int mg = (b & 7) >> 1;               // 0..3
    const int nb = ((b >> 3) << 1) | (b & 1);  // 0..63
    const int m0 = mg * 128;
    const int n0 = nb * 64;
    const int jb = nb * 16;
    const int w = tid >> 6;
    const int lane = tid & 63;
    const int quad = lane >> 4;
    const int l16 = lane & 15;

    // stage W_hh tile (64 cols x K=1024) into LDS once
#pragma unroll 4
    for (int i = 0; i < 32; ++i) {
        int u = i * 256 + tid;  // 16B units: 64 rows x 128 units
        int c = u >> 7;
        int kc = u & 127;
        uint4 v = *(const uint4*)(WcT + (size_t)(n0 + c) * 1536 + 512 + kc * 8);
        *(uint4*)&Ws[c][kc * 8] = v;
    }

    // chunk-resident state
    float creg[8], hmx[8];
    const int rbase = m0 + w * 32 + quad * 4;  // + mi*16 + rg
#pragma unroll
    for (int idx = 0; idx < 8; ++idx) {
        int row = rbase + (idx >> 2) * 16 + (idx & 3);
        creg[idx] = C[(size_t)row * 1024 + jb + l16];
        hmx[idx] = HMAX[(size_t)row * 1024 + jb + l16];
    }
    __syncthreads();  // Ws ready

#pragma unroll 1
    for (int st = 0; st < 8; ++st) {
        const int t = t0 + st;
        const ushort* Hin = Hbuf + ((size_t)(t & 1) << 19);
        ushort* Hout = Hbuf + ((size_t)((t + 1) & 1) << 19);

        // Xb pre-acts (bias included), L2-resident
        ushort xbv[8][4];
        const ushort* xbase =
            Xb + (size_t)(st * 512 + rbase) * 4096 + n0 + l16;
#pragma unroll
        for (int idx = 0; idx < 8; ++idx) {
            const ushort* xr =
                xbase + (size_t)((idx >> 2) * 16 + (idx & 3)) * 4096;
#pragma unroll
            for (int g = 0; g < 4; ++g) xbv[idx][g] = xr[g * 16];
        }

        f32x4 acc[2][4] = {};
        const ushort* arow0 =
            Hin + (size_t)(m0 + w * 32 + l16) * 1024 + quad * 8;
        const ushort* arow1 = arow0 + 16 * 1024;

        bf16x8 apf[8][2];
        bf16x8 bpf[4][4];
#pragma unroll
        for (int s = 0; s < 8; ++s) {
            apf[s][0] = *(const bf16x8*)(arow0 + s * 32);
            apf[s][1] = *(const bf16x8*)(arow1 + s * 32);
        }
#pragma unroll
        for (int s = 0; s < 4; ++s)
#pragma unroll
            for (int ni = 0; ni < 4; ++ni)
                bpf[s][ni] =
                    *(const bf16x8*)&Ws[ni * 16 + l16][s * 32 + quad * 8];

#pragma unroll
        for (int s = 0; s < 32; ++s) {
            bf16x8 a0 = apf[s & 7][0];
            bf16x8 a1 = apf[s & 7][1];
            bf16x8 b0 = bpf[s & 3][0];
            bf16x8 b1 = bpf[s & 3][1];
            bf16x8 b2 = bpf[s & 3][2];
            bf16x8 b3 = bpf[s & 3][3];
            if (s + 8 < 32) {
                apf[s & 7][0] = *(const bf16x8*)(arow0 + (s + 8) * 32);
                apf[s & 7][1] = *(const bf16x8*)(arow1 + (s + 8) * 32);
            }
            if (s + 4 < 32) {
#pragma unroll
                for (int ni = 0; ni < 4; ++ni)
                    bpf[s & 3][ni] = *(const bf16x8*)&Ws[ni * 16 + l16]
                                                       [(s + 4) * 32 + quad * 8];
            }
            acc[0][0] = __builtin_amdgcn_mfma_f32_16x16x32_bf16(a0, b0, acc[0][0], 0, 0, 0);
            acc[0][1] = __builtin_amdgcn_mfma_f32_16x16x32_bf16(a0, b1, acc[0][1], 0, 0, 0);
            acc[0][2] = __builtin_amdgcn_mfma_f32_16x16x32_bf16(a0, b2, acc[0][2], 0, 0, 0);
            acc[0][3] = __builtin_amdgcn_mfma_f32_16x16x32_bf16(a0, b3, acc[0][3], 0, 0, 0);
            acc[1][0] = __builtin_amdgcn_mfma_f32_16x16x32_bf16(a1, b0, acc[1][0], 0, 0, 0);
            acc[1][1] = __builtin_amdgcn_mfma_f32_16x16x32_bf16(a1, b1, acc[1][1], 0, 0, 0);
            acc[1][2] = __builtin_amdgcn_mfma_f32_16x16x32_bf16(a1, b2, acc[1][2], 0, 0, 0);
            acc[1][3] = __builtin_amdgcn_mfma_f32_16x16x32_bf16(a1, b3, acc[1][3], 0, 0, 0);
        }

        // fused cell update, all registers
#pragma unroll
        for (int idx = 0; idx < 8; ++idx) {
            const int mi = idx >> 2;
            const int rg = idx & 3;
            float gi = acc[mi][0][rg] + bu2f(xbv[idx][0]);
            float gf = acc[mi][1][rg] + bu2f(xbv[idx][1]);
            float gg = acc[mi][2][rg] + bu2f(xbv[idx][2]);
            float go = acc[mi][3][rg] + bu2f(xbv[idx][3]);
            float cn = sigm(gf) * creg[idx] + sigm(gi) * tanh_fast(gg);
            float h = sigm(go) * tanh_fast(cn);
            creg[idx] = cn;
            hmx[idx] = fmaxf(hmx[idx], h);
            int row = rbase + mi * 16 + rg;
            Hout[(size_t)row * 1024 + jb + l16] = f2bu(h);
        }

        // per-m-group barrier (64 blocks), skip after last step
        if (st < 7) {
            __threadfence();   // each wave: drain + write back own h stores
            __syncthreads();   // all waves of this block flushed
            if (tid == 0) {
                atomicAdd(&bcnt[mg], 1);
                const int target = tgt0 + 64 * (st + 1);
                while (__hip_atomic_load(&bcnt[mg], __ATOMIC_RELAXED,
                                         __HIP_MEMORY_SCOPE_AGENT) < target) {
                    __builtin_amdgcn_s_sleep(2);
                }
            }
            __syncthreads();
            __threadfence();   // acquire: invalidate stale cached h lines
        }
    }

    // spill chunk state
#pragma unroll
    for (int idx = 0; idx < 8; ++idx) {
        int row = rbase + (idx >> 2) * 16 + (idx & 3);
        C[(size_t)row * 1024 + jb + l16] = creg[idx];
        HMAX[(size_t)row * 1024 + jb + l16] = hmx[idx];
    }
}

// ---------------------------------------------------------------------------
// Kernel 6: final linear + sigmoid.
// ---------------------------------------------------------------------------
__global__ void final_out(const float* __restrict__ HMAX,
                          const float* __restrict__ Wl,
                          const float* __restrict__ bl,
                          float* __restrict__ out) {
    int b = blockIdx.x;
    int tid = threadIdx.x;
    float s0 = 0.0f, s1 = 0.0f;
    for (int j = tid; j < 1024; j += 256) {
        float hq = HMAX[(size_t)b * 1024 + j];
        float hs = HMAX[(size_t)(256 + b) * 1024 + j];
        s0 += hq * Wl[j] + hs * Wl[1024 + j];
        s1 += hq * Wl[2048 + j] + hs * Wl[3072 + j];
    }
    __shared__ float r0[256], r1[256];
    r0[tid] = s0;
    r1[tid] = s1;
    __syncthreads();
    for (int off = 128; off > 0; off >>= 1) {
        if (tid < off) {
            r0[tid] += r0[tid + off];
            r1[tid] += r1[tid + off];
        }
        __syncthreads();
    }
    if (tid == 0) {
        out[b * 2 + 0] = sigm(r0[0] + bl[0]);
        out[b * 2 + 1] = sigm(r1[0] + bl[1]);
    }
}

// ---------------------------------------------------------------------------
extern "C" void kernel_launch(void* const* d_in, const int* in_sizes, int n_in,
                              void* d_out, int out_size, void* d_ws,
                              size_t ws_size, hipStream_t stream) {
    const int* q = (const int*)d_in[0];
    const int* s = (const int*)d_in[1];
    const float* emb = (const float*)d_in[2];
    const float* Wih = (const float*)d_in[3];
    const float* Whh = (const float*)d_in[4];
    const float* bih = (const float*)d_in[5];
    const float* bhh = (const float*)d_in[6];
    const float* Wl = (const float*)d_in[7];
    const float* bl = (const float*)d_in[8];
    float* out = (float*)d_out;

    // workspace layout (bytes, 16B-aligned); total 56,639,744 (< R2-proven
    // 119,554,048)
    char* ws = (char*)d_ws;
    __hip_bfloat16* WcT = (__hip_bfloat16*)(ws + 0);  // 12,582,912
    float* biasc = (float*)(ws + 12582912);           //     16,384
    ushort* Xc = (ushort*)(ws + 12599296);            //  4,194,304
    ushort* Xb = (ushort*)(ws + 16793600);            // 33,554,432
    ushort* Hbuf = (ushort*)(ws + 50348032);          //  2,097,152
    float* C = (float*)(ws + 52445184);               //  2,097,152
    float* HMAX = (float*)(ws + 54542336);            //  2,097,152
    int* counters = (int*)(ws + 56639488);            //        256

    prep_weights<<<dim3(6, 4096), 256, 0, stream>>>(Wih, Whh, bih, bhh, WcT,
                                                    biasc);
    init_state<<<2048, 256, 0, stream>>>(C, HMAX, Hbuf, counters);

    for (int c = 0; c < 16; ++c) {
        gather_chunk<<<4096, 256, 0, stream>>>(q, s, emb, Xc, c * 8);
        xproj_gemm<<<dim3(32, 32), 256, 0, stream>>>(Xc, (const ushort*)WcT,
                                                     biasc, Xb);
        lstm_chunk<<<256, 256, 0, stream>>>(Xb, (const ushort*)WcT, Hbuf, C,
                                            HMAX, counters, c * 8,
                                            c * 7 * 64);
    }
    final_out<<<256, 256, 0, stream>>>(HMAX, Wl, bl, out);
}